// Round 2
// baseline (970.578 us; speedup 1.0000x reference)
//
#include <hip/hip_runtime.h>
#include <math.h>

#define B_  128
#define S_  512
#define U_  1024
#define T_  48

// ---------------------------------------------------------------------------
// Kernel 1: scores[b,s,t] = sum_u H[b,s,u] * W[u,t] + bias[t]
// 4 lanes per row, each computing 12 of the 48 outputs (12 VGPR accumulators
// -> no register-pressure pathology; round-1's acc[48] left VGPR_Count=44,
// i.e. the compiler split the loop and re-streamed H: 458us, VALUBusy 9%).
// Lanes 4i..4i+3 share an H row -> h loads broadcast-coalesce.
// Rows with s >= s_len[b] are skipped entirely (CRF never reads them).
// ---------------------------------------------------------------------------
__global__ __launch_bounds__(256) void gemm_scores(
    const float* __restrict__ H, const float* __restrict__ W,
    const float* __restrict__ bias, const int* __restrict__ s_len,
    float* __restrict__ scores)
{
    const int gid  = blockIdx.x * 256 + threadIdx.x;   // 0..262143
    const int row  = gid >> 2;                         // 0..65535
    const int tgrp = gid & 3;
    const int toff = tgrp * 12;

    const int b = row >> 9;          // row / S_
    const int s = row & (S_ - 1);    // row % S_
    if (s >= s_len[b]) return;       // CRF only reads s < len

    const float4* h4 = reinterpret_cast<const float4*>(H + (size_t)row * U_);

    float acc[12];
#pragma unroll
    for (int t = 0; t < 12; ++t) acc[t] = 0.f;

    for (int k4 = 0; k4 < U_ / 4; ++k4) {
        const float4 h = h4[k4];
        const float* wp = W + k4 * 4 * T_ + toff;
#pragma unroll
        for (int r = 0; r < 4; ++r) {
            const float hr = (r == 0) ? h.x : (r == 1) ? h.y : (r == 2) ? h.z : h.w;
            const float4 w0 = *reinterpret_cast<const float4*>(wp + r * T_ + 0);
            const float4 w1 = *reinterpret_cast<const float4*>(wp + r * T_ + 4);
            const float4 w2 = *reinterpret_cast<const float4*>(wp + r * T_ + 8);
            acc[0]  = fmaf(hr, w0.x, acc[0]);
            acc[1]  = fmaf(hr, w0.y, acc[1]);
            acc[2]  = fmaf(hr, w0.z, acc[2]);
            acc[3]  = fmaf(hr, w0.w, acc[3]);
            acc[4]  = fmaf(hr, w1.x, acc[4]);
            acc[5]  = fmaf(hr, w1.y, acc[5]);
            acc[6]  = fmaf(hr, w1.z, acc[6]);
            acc[7]  = fmaf(hr, w1.w, acc[7]);
            acc[8]  = fmaf(hr, w2.x, acc[8]);
            acc[9]  = fmaf(hr, w2.y, acc[9]);
            acc[10] = fmaf(hr, w2.z, acc[10]);
            acc[11] = fmaf(hr, w2.w, acc[11]);
        }
    }

    float* out = scores + (size_t)row * T_ + toff;
#pragma unroll
    for (int t = 0; t < 12; ++t) out[t] = acc[t] + bias[toff + t];
}

// ---------------------------------------------------------------------------
// Kernel 2: CRF forward + numerator. One wave (64 lanes) per batch.
// Linear-domain recursion with running log-scale C:
//   q_t = (sum_j p_j * E[j][t]) * exp(emit_t);  r = q[lane0];
//   p = q / r;  C += log(r)            (log(r) is off the serial chain)
// Emits for the next 8 steps are prefetched and exp'ed in a batch, so the
// dependent global load / exp / log of round 1 leave the per-step chain.
// Block = exactly 1 wave -> no __syncthreads in the hot loop (in-order DS).
// ---------------------------------------------------------------------------
__global__ __launch_bounds__(64) void crf_forward(
    const float* __restrict__ scores, const float* __restrict__ start_tr,
    const float* __restrict__ end_tr, const float* __restrict__ trans,
    const int* __restrict__ tag, const int* __restrict__ s_len,
    float* __restrict__ out)
{
    __shared__ float E[T_ * T_];
    __shared__ float Tr[T_ * T_];
    __shared__ __align__(16) float abuf[64];

    const int b    = blockIdx.x;
    const int lane = threadIdx.x;

    for (int i = lane; i < T_ * T_; i += 64) {
        const float v = trans[i];
        Tr[i] = v;
        E[i]  = __expf(v);
    }
    __syncthreads();   // once (staging), cheap

    const int len = s_len[b];                      // in [1, S]
    const float* sc = scores + (size_t)b * S_ * T_;
    const int*   tg = tag + (size_t)b * S_;

    // ---- numerator: emit-at-tag + transition pairs, parallel over s ----
    float nsum = 0.f;
    for (int s = lane; s < len; s += 64) {
        const int t = tg[s];
        nsum += sc[s * T_ + t];
        if (s >= 1) nsum += Tr[tg[s - 1] * T_ + t];
    }
#pragma unroll
    for (int off = 32; off >= 1; off >>= 1)
        nsum += __shfl_xor(nsum, off);

    // ---- E column for this lane in registers ----
    const int col = (lane < T_) ? lane : 0;
    float e[T_];
#pragma unroll
    for (int j = 0; j < T_; ++j) e[j] = E[j * T_ + col];

    // ---- init (shift by lane0's value; spread is bounded ~e^16, safe) ----
    const float lp0 = (lane < T_) ? (start_tr[lane] + sc[lane]) : -1e30f;
    const float m0  = __shfl(lp0, 0);
    float p = __expf(lp0 - m0);                    // lanes>=48 -> 0
    float C = m0;

    constexpr int PF = 8;
    int s = 1;
    while (s < len) {
        const int n = (len - s < PF) ? (len - s) : PF;
        float eem[PF];
#pragma unroll
        for (int i = 0; i < PF; ++i)
            if (i < n) eem[i] = __expf(sc[(s + i) * T_ + col]);

#pragma unroll
        for (int i = 0; i < PF; ++i) {
            if (i < n) {
                abuf[lane] = p;
                __builtin_amdgcn_wave_barrier();
                float s0 = 0.f, s1 = 0.f, s2 = 0.f, s3 = 0.f;
                const float4* a4 = reinterpret_cast<const float4*>(abuf);
#pragma unroll
                for (int j4 = 0; j4 < T_ / 4; ++j4) {
                    const float4 pv = a4[j4];
                    s0 = fmaf(pv.x, e[4 * j4 + 0], s0);
                    s1 = fmaf(pv.y, e[4 * j4 + 1], s1);
                    s2 = fmaf(pv.z, e[4 * j4 + 2], s2);
                    s3 = fmaf(pv.w, e[4 * j4 + 3], s3);
                }
                __builtin_amdgcn_wave_barrier();
                const float q = ((s0 + s1) + (s2 + s3)) * eem[i];
                const float r = __shfl(q, 0);
                C += __logf(r);                    // off the p-chain (ILP)
                const float rinv = __builtin_amdgcn_rcpf(r);
                p = (lane < T_) ? q * rinv : 0.f;
            }
        }
        s += n;
    }

    // ---- log_Z = C + log(sum_t p_t * exp(end_t)) ----
    float z = (lane < T_) ? p * __expf(end_tr[lane]) : 0.f;
#pragma unroll
    for (int off = 32; off >= 1; off >>= 1)
        z += __shfl_xor(z, off);
    const float logZ = C + __logf(z);

    if (lane == 0) {
        const float num = nsum + start_tr[tg[0]] + end_tr[tg[len - 1]];
        out[b] = num - logZ;
    }
}

// ---------------------------------------------------------------------------
extern "C" void kernel_launch(void* const* d_in, const int* in_sizes, int n_in,
                              void* d_out, int out_size, void* d_ws, size_t ws_size,
                              hipStream_t stream) {
    const float* H        = (const float*)d_in[0];
    const float* W        = (const float*)d_in[1];
    const float* bias     = (const float*)d_in[2];
    const float* start_tr = (const float*)d_in[3];
    const float* end_tr   = (const float*)d_in[4];
    const float* trans    = (const float*)d_in[5];
    const int*   tag      = (const int*)d_in[6];
    const int*   s_len    = (const int*)d_in[7];
    // d_in[8] = w_mask, redundant with s_len

    float* scores = (float*)d_ws;   // 65536 x 48 fp32 = 12.6 MB

    hipLaunchKernelGGL(gemm_scores, dim3((B_ * S_ * 4) / 256), dim3(256), 0, stream,
                       H, W, bias, s_len, scores);
    hipLaunchKernelGGL(crf_forward, dim3(B_), dim3(64), 0, stream,
                       scores, start_tr, end_tr, trans, tag, s_len, (float*)d_out);
}

// Round 3
// 542.665 us; speedup vs baseline: 1.7885x; 1.7885x over previous
//
#include <hip/hip_runtime.h>
#include <math.h>

#define B_  128
#define S_  512
#define U_  1024
#define T_  48

// ===========================================================================
// Kernel 1: scores = H @ W + b, LDS-tiled.
// Rounds 1-2 failed at 450us because each lane privately streamed its own H
// row: 16 scattered 16B segments per load instruction, latency-bound
// (VALUBusy 5%, HBM 2%). This version loads H coalesced (16 lanes = 256B of
// one row), stages transposed into LDS, and register-blocks 8 rows x 3 cols
// per thread -> VALU-bound.
// ===========================================================================
#define TILE_R 128
#define KC     64
#define HS_LD  132   // 128 + 4: multiple of 4 (b128 align), breaks write conflicts to 8-way

__global__ __launch_bounds__(256) void gemm_scores(
    const float* __restrict__ H, const float* __restrict__ W,
    const float* __restrict__ bias, const int* __restrict__ s_len,
    float* __restrict__ scores)
{
    __shared__ float Hs[KC * HS_LD];   // transposed: Hs[k][row], 33.8 KB
    __shared__ float Ws[KC * T_];      // Ws[k][t], 12.3 KB

    const int blk = blockIdx.x;        // 512 blocks
    const int b   = blk >> 2;
    const int s0  = (blk & 3) * TILE_R;
    if (s0 >= s_len[b]) return;        // uniform exit before any barrier

    const int tid  = threadIdx.x;
    const int tr   = tid >> 4;         // 0..15 -> rows 8tr .. 8tr+7
    const int tc   = tid & 15;         // cols tc, tc+16, tc+32
    const int srow = tid >> 4;         // staging: row sub-index
    const int seg  = tid & 15;         // staging: float4 segment in k-chunk

    const size_t row0 = (size_t)b * S_ + s0;
    const float4* Hg4 = reinterpret_cast<const float4*>(H + row0 * U_);

    float acc[8][3];
#pragma unroll
    for (int i = 0; i < 8; ++i)
#pragma unroll
        for (int j = 0; j < 3; ++j) acc[i][j] = 0.f;

    for (int kc = 0; kc < U_ / KC; ++kc) {
        const int k0 = kc * KC;

        // ---- stage W chunk: 64x48 floats, flat coalesced copy ----
        const float4* Wg4 = reinterpret_cast<const float4*>(W + (size_t)k0 * T_);
        float4* Ws4 = reinterpret_cast<float4*>(Ws);
#pragma unroll
        for (int i = 0; i < 3; ++i)
            Ws4[tid + 256 * i] = Wg4[tid + 256 * i];

        // ---- stage H chunk transposed: 128 rows x 64 k ----
#pragma unroll
        for (int p = 0; p < 8; ++p) {
            const int row = p * 16 + srow;
            const float4 h = Hg4[(size_t)row * (U_ / 4) + (k0 / 4) + seg];
            const int kk = 4 * seg;
            Hs[(kk + 0) * HS_LD + row] = h.x;
            Hs[(kk + 1) * HS_LD + row] = h.y;
            Hs[(kk + 2) * HS_LD + row] = h.z;
            Hs[(kk + 3) * HS_LD + row] = h.w;
        }
        __syncthreads();

        // ---- compute: per k-step 2x ds_read_b128 (h) + 3x b32 (w), 24 FMA ----
#pragma unroll 4
        for (int kk = 0; kk < KC; ++kk) {
            const float4 h0 = *reinterpret_cast<const float4*>(&Hs[kk * HS_LD + 8 * tr]);
            const float4 h1 = *reinterpret_cast<const float4*>(&Hs[kk * HS_LD + 8 * tr + 4]);
            const float w0 = Ws[kk * T_ + tc];
            const float w1 = Ws[kk * T_ + tc + 16];
            const float w2 = Ws[kk * T_ + tc + 32];
            acc[0][0] = fmaf(h0.x, w0, acc[0][0]); acc[0][1] = fmaf(h0.x, w1, acc[0][1]); acc[0][2] = fmaf(h0.x, w2, acc[0][2]);
            acc[1][0] = fmaf(h0.y, w0, acc[1][0]); acc[1][1] = fmaf(h0.y, w1, acc[1][1]); acc[1][2] = fmaf(h0.y, w2, acc[1][2]);
            acc[2][0] = fmaf(h0.z, w0, acc[2][0]); acc[2][1] = fmaf(h0.z, w1, acc[2][1]); acc[2][2] = fmaf(h0.z, w2, acc[2][2]);
            acc[3][0] = fmaf(h0.w, w0, acc[3][0]); acc[3][1] = fmaf(h0.w, w1, acc[3][1]); acc[3][2] = fmaf(h0.w, w2, acc[3][2]);
            acc[4][0] = fmaf(h1.x, w0, acc[4][0]); acc[4][1] = fmaf(h1.x, w1, acc[4][1]); acc[4][2] = fmaf(h1.x, w2, acc[4][2]);
            acc[5][0] = fmaf(h1.y, w0, acc[5][0]); acc[5][1] = fmaf(h1.y, w1, acc[5][1]); acc[5][2] = fmaf(h1.y, w2, acc[5][2]);
            acc[6][0] = fmaf(h1.z, w0, acc[6][0]); acc[6][1] = fmaf(h1.z, w1, acc[6][1]); acc[6][2] = fmaf(h1.z, w2, acc[6][2]);
            acc[7][0] = fmaf(h1.w, w0, acc[7][0]); acc[7][1] = fmaf(h1.w, w1, acc[7][1]); acc[7][2] = fmaf(h1.w, w2, acc[7][2]);
        }
        __syncthreads();
    }

    // ---- epilogue ----
    const float b0 = bias[tc], b1 = bias[tc + 16], b2 = bias[tc + 32];
#pragma unroll
    for (int i = 0; i < 8; ++i) {
        float* o = scores + (row0 + 8 * tr + i) * T_ + tc;
        o[0]  = acc[i][0] + b0;
        o[16] = acc[i][1] + b1;
        o[32] = acc[i][2] + b2;
    }
}

// ===========================================================================
// Kernel 2: CRF forward + numerator. One wave per batch.
// Lag-1 normalization: the readfirstlane/rcp/log of the normalizer run one
// step behind the recursion, so the serial chain is only
//   ds_write(v) -> 12x ds_read_b128(broadcast) -> 12-deep FMA -> *eem -> *invr
// Exact bookkeeping: alpha_s = v * e^C maintained at every step.
// ===========================================================================
__device__ __forceinline__ float rfl(float x) {
    return __int_as_float(__builtin_amdgcn_readfirstlane(__float_as_int(x)));
}

__global__ __launch_bounds__(64) void crf_forward(
    const float* __restrict__ scores, const float* __restrict__ start_tr,
    const float* __restrict__ end_tr, const float* __restrict__ trans,
    const int* __restrict__ tag, const int* __restrict__ s_len,
    float* __restrict__ out)
{
    __shared__ float E[T_ * T_];
    __shared__ float Tr[T_ * T_];
    __shared__ __align__(16) float abuf[64];

    const int b    = blockIdx.x;
    const int lane = threadIdx.x;

    for (int i = lane; i < T_ * T_; i += 64) {
        const float t = trans[i];
        Tr[i] = t;
        E[i]  = __expf(t);
    }
    __syncthreads();

    const int len = s_len[b];                       // in [1, S]
    const float* sc = scores + (size_t)b * S_ * T_;
    const int*   tg = tag + (size_t)b * S_;

    // ---- numerator ----
    float nsum = 0.f;
    for (int s = lane; s < len; s += 64) {
        const int t = tg[s];
        nsum += sc[s * T_ + t];
        if (s >= 1) nsum += Tr[tg[s - 1] * T_ + t];
    }
#pragma unroll
    for (int off = 32; off >= 1; off >>= 1)
        nsum += __shfl_xor(nsum, off);

    // ---- E column in registers ----
    const int col = (lane < T_) ? lane : 0;
    float e[T_];
#pragma unroll
    for (int j = 0; j < T_; ++j) e[j] = E[j * T_ + col];

    // ---- init ----
    const float lp0 = (lane < T_) ? (start_tr[lane] + sc[lane]) : -1e30f;
    const float m0  = rfl(lp0);
    float v = __expf(lp0 - m0);                     // lanes>=48 -> 0
    float C = m0;
    float invp = 1.0f, lrp = 0.0f;                  // pending (lag-1) scale

#define CRF_STEP(EM)                                                       \
    {                                                                      \
        abuf[lane] = v;                                                    \
        __builtin_amdgcn_wave_barrier();                                   \
        const float4* a4 = reinterpret_cast<const float4*>(abuf);          \
        float d0 = 0.f, d1 = 0.f, d2 = 0.f, d3 = 0.f;                      \
        _Pragma("unroll")                                                  \
        for (int j4 = 0; j4 < T_ / 4; ++j4) {                              \
            const float4 pv = a4[j4];                                      \
            d0 = fmaf(pv.x, e[4 * j4 + 0], d0);                            \
            d1 = fmaf(pv.y, e[4 * j4 + 1], d1);                            \
            d2 = fmaf(pv.z, e[4 * j4 + 2], d2);                            \
            d3 = fmaf(pv.w, e[4 * j4 + 3], d3);                            \
        }                                                                  \
        __builtin_amdgcn_wave_barrier();                                   \
        const float w = ((d0 + d1) + (d2 + d3)) * (EM);                    \
        v = w * invp;                                                      \
        C += lrp;                                                          \
        const float r = rfl(v);     /* off-chain: consumed next step */    \
        invp = __builtin_amdgcn_rcpf(r);                                   \
        lrp  = __logf(r);                                                  \
    }

    constexpr int PF = 8;
    int s = 1;
    while (s + PF <= len) {
        float em[PF];
#pragma unroll
        for (int i = 0; i < PF; ++i) em[i] = __expf(sc[(s + i) * T_ + col]);
#pragma unroll
        for (int i = 0; i < PF; ++i) CRF_STEP(em[i]);
        s += PF;
    }
    while (s < len) {
        const float em1 = __expf(sc[s * T_ + col]);
        CRF_STEP(em1);
        ++s;
    }
#undef CRF_STEP

    // ---- log_Z = C + log(sum_t v_t * exp(end_t)) ----
    float z = (lane < T_) ? v * __expf(end_tr[lane]) : 0.f;
#pragma unroll
    for (int off = 32; off >= 1; off >>= 1)
        z += __shfl_xor(z, off);
    const float logZ = C + __logf(z);

    if (lane == 0) {
        const float num = nsum + start_tr[tg[0]] + end_tr[tg[len - 1]];
        out[b] = num - logZ;
    }
}

// ---------------------------------------------------------------------------
extern "C" void kernel_launch(void* const* d_in, const int* in_sizes, int n_in,
                              void* d_out, int out_size, void* d_ws, size_t ws_size,
                              hipStream_t stream) {
    const float* H        = (const float*)d_in[0];
    const float* W        = (const float*)d_in[1];
    const float* bias     = (const float*)d_in[2];
    const float* start_tr = (const float*)d_in[3];
    const float* end_tr   = (const float*)d_in[4];
    const float* trans    = (const float*)d_in[5];
    const int*   tag      = (const int*)d_in[6];
    const int*   s_len    = (const int*)d_in[7];
    // d_in[8] = w_mask, redundant with s_len

    float* scores = (float*)d_ws;   // 65536 x 48 fp32 = 12.6 MB

    hipLaunchKernelGGL(gemm_scores, dim3((B_ * S_) / TILE_R), dim3(256), 0, stream,
                       H, W, bias, s_len, scores);
    hipLaunchKernelGGL(crf_forward, dim3(B_), dim3(64), 0, stream,
                       scores, start_tr, end_tr, trans, tag, s_len, (float*)d_out);
}

// Round 4
// 495.945 us; speedup vs baseline: 1.9570x; 1.0942x over previous
//
#include <hip/hip_runtime.h>
#include <math.h>

#define B_  128
#define S_  512
#define U_  1024
#define T_  48

typedef short  bf16x8 __attribute__((ext_vector_type(8)));
typedef float  f32x4  __attribute__((ext_vector_type(4)));

// round-to-nearest fp32 -> bf16 bits, packed pairwise via v_perm
__device__ __forceinline__ unsigned pack_bf16(float lo, float hi) {
    const unsigned a = __float_as_uint(lo) + 0x8000u;
    const unsigned b = __float_as_uint(hi) + 0x8000u;
    return __builtin_amdgcn_perm(b, a, 0x07060302u);  // [b.hi16 : a.hi16]
}

// ===========================================================================
// Kernel 0: Wt[n][k] = bf16(W[k][n])  (48 x 1024, 96 KB) — one-time transpose
// so gemm's B-fragment staging is coalesced bf16 b128 loads.
// ===========================================================================
__global__ __launch_bounds__(256) void prep_w(
    const float* __restrict__ W, unsigned short* __restrict__ Wt)
{
    const int n = blockIdx.x;                 // 48 blocks
#pragma unroll
    for (int i = 0; i < 4; ++i) {
        const int k = threadIdx.x + 256 * i;
        const unsigned u = __float_as_uint(W[(size_t)k * T_ + n]) + 0x8000u;
        Wt[(size_t)n * U_ + k] = (unsigned short)(u >> 16);
    }
}

// ===========================================================================
// Kernel 1: scores = H @ W + b (fp32 out) AND emit = exp(scores).
// MFMA bf16 16x16x32. Round-3's fp32 version was LDS-issue-bound
// (41 DS-cyc per 24 FMA); MFMA gives 8192 FLOP per 2x ds_read_b128,
// leaving the kernel HBM-bound on the H stream (~160 MB active).
// Block: 256 thr = 4 waves, tile 128 rows x 48 cols, KC=64.
// ===========================================================================
#define KC     64
#define HS_LD  72    // bf16 elems/row: 64 + 8 pad -> 144 B (16B-aligned rows)
#define WS_LD  72

__global__ __launch_bounds__(256) void gemm_scores_mfma(
    const float* __restrict__ H, const unsigned short* __restrict__ Wt,
    const float* __restrict__ bias, const int* __restrict__ s_len,
    float* __restrict__ scores, float* __restrict__ emit)
{
    __shared__ unsigned short Hs[128 * HS_LD];  // 18.4 KB
    __shared__ unsigned short Ws[T_ * WS_LD];   //  6.9 KB

    const int blk = blockIdx.x;         // 512 blocks
    const int b   = blk >> 2;
    const int s0  = (blk & 3) * 128;
    if (s0 >= s_len[b]) return;         // block-uniform exit (before barriers)

    const int tid  = threadIdx.x;
    const int wave = tid >> 6;
    const int lane = tid & 63;
    const int m16  = lane & 15;         // MFMA row / col within tile
    const int q    = lane >> 4;         // MFMA k-quad
    const int grp  = tid >> 4;          // staging: row group 0..15
    const int l16  = tid & 15;          // staging: 4-float segment

    const size_t row0 = (size_t)b * S_ + s0;
    const float* Hg = H + row0 * U_;

    f32x4 acc[2][3];
#pragma unroll
    for (int mt = 0; mt < 2; ++mt)
#pragma unroll
        for (int nt = 0; nt < 3; ++nt) acc[mt][nt] = (f32x4){0.f, 0.f, 0.f, 0.f};

    for (int kc = 0; kc < U_ / KC; ++kc) {
        const int k0 = kc * KC;

        // ---- stage H chunk (128 x 64 fp32 -> bf16): coalesced 256B/row ----
#pragma unroll
        for (int p = 0; p < 8; ++p) {
            const int row = p * 16 + grp;
            const float4 h = *reinterpret_cast<const float4*>(
                Hg + (size_t)row * U_ + k0 + l16 * 4);
            const unsigned p01 = pack_bf16(h.x, h.y);
            const unsigned p23 = pack_bf16(h.z, h.w);
            *reinterpret_cast<uint2*>(&Hs[row * HS_LD + l16 * 4]) =
                make_uint2(p01, p23);
        }
        // ---- stage W chunk (48 x 64 bf16) from pre-transposed Wt ----
#pragma unroll
        for (int i = 0; i < 2; ++i) {
            const int idx = tid + 256 * i;
            if (idx < 384) {
                const int n = idx >> 3, seg = idx & 7;
                const uint4 w = *reinterpret_cast<const uint4*>(
                    Wt + (size_t)n * U_ + k0 + seg * 8);
                *reinterpret_cast<uint4*>(&Ws[n * WS_LD + seg * 8]) = w;
            }
        }
        __syncthreads();

        // ---- fragments + 12 MFMA ----
        bf16x8 afr[2][2], bfr[3][2];
#pragma unroll
        for (int mt = 0; mt < 2; ++mt)
#pragma unroll
            for (int ks = 0; ks < 2; ++ks)
                afr[mt][ks] = *reinterpret_cast<const bf16x8*>(
                    &Hs[(wave * 32 + mt * 16 + m16) * HS_LD + ks * 32 + q * 8]);
#pragma unroll
        for (int nt = 0; nt < 3; ++nt)
#pragma unroll
            for (int ks = 0; ks < 2; ++ks)
                bfr[nt][ks] = *reinterpret_cast<const bf16x8*>(
                    &Ws[(nt * 16 + m16) * WS_LD + ks * 32 + q * 8]);
#pragma unroll
        for (int ks = 0; ks < 2; ++ks)
#pragma unroll
            for (int mt = 0; mt < 2; ++mt)
#pragma unroll
                for (int nt = 0; nt < 3; ++nt)
                    acc[mt][nt] = __builtin_amdgcn_mfma_f32_16x16x32_bf16(
                        afr[mt][ks], bfr[nt][ks], acc[mt][nt], 0, 0, 0);
        __syncthreads();
    }

    // ---- epilogue: C/D layout col=lane&15, row=q*4+reg ----
#pragma unroll
    for (int mt = 0; mt < 2; ++mt) {
#pragma unroll
        for (int nt = 0; nt < 3; ++nt) {
            const int col = nt * 16 + m16;
            const float bv = bias[col];
#pragma unroll
            for (int i = 0; i < 4; ++i) {
                const size_t r = row0 + wave * 32 + mt * 16 + q * 4 + i;
                const float v = acc[mt][nt][i] + bv;
                scores[r * T_ + col] = v;
                emit[r * T_ + col]   = __expf(v);
            }
        }
    }
}

// ===========================================================================
// Kernel 2: CRF forward + numerator. One wave per batch.
// Serial chain per step: 12x ds_read_b128 (broadcast) -> 8-acc FMA (depth 6)
// -> 3-level tree -> 1 mul (em*invr, both prepared a step early) -> ds_write.
// exp() is gone from the loop (emit precomputed by gemm); normalizer
// readfirstlane/rcp/log all run lag-1, off the chain.
// ===========================================================================
__device__ __forceinline__ float rfl(float x) {
    return __int_as_float(__builtin_amdgcn_readfirstlane(__float_as_int(x)));
}

__global__ __launch_bounds__(64) void crf_forward(
    const float* __restrict__ scores, const float* __restrict__ emit,
    const float* __restrict__ start_tr, const float* __restrict__ end_tr,
    const float* __restrict__ trans, const int* __restrict__ tag,
    const int* __restrict__ s_len, float* __restrict__ out)
{
    __shared__ float E[T_ * T_];
    __shared__ float Tr[T_ * T_];
    __shared__ __align__(16) float wb[2][64];

    const int b    = blockIdx.x;
    const int lane = threadIdx.x;

    for (int i = lane; i < T_ * T_; i += 64) {
        const float t = trans[i];
        Tr[i] = t;
        E[i]  = __expf(t);
    }
    __syncthreads();

    const int len = s_len[b];                        // [1, S]
    const float* sc = scores + (size_t)b * S_ * T_;
    const float* em = emit   + (size_t)b * S_ * T_;
    const int*   tg = tag + (size_t)b * S_;

    // ---- numerator (parallel over s) ----
    float nsum = 0.f;
    for (int s = lane; s < len; s += 64) {
        const int t = tg[s];
        nsum += sc[s * T_ + t];
        if (s >= 1) nsum += Tr[tg[s - 1] * T_ + t];
    }
#pragma unroll
    for (int off = 32; off >= 1; off >>= 1)
        nsum += __shfl_xor(nsum, off);

    // ---- E column in registers ----
    const int col = (lane < T_) ? lane : 0;
    float e[T_];
#pragma unroll
    for (int j = 0; j < T_; ++j) e[j] = E[j * T_ + col];

    // ---- init: w_0 = exp(lp0 - m0); lane0 exactly 1 -> invr=1, lr=0 ----
    const float lp0 = (lane < T_) ? (start_tr[lane] + sc[lane]) : -1e30f;
    const float m0  = rfl(lp0);
    float v = __expf(lp0 - m0);
    float C = m0;
    float invr = 1.0f, lr = 0.0f;

#define CRF_STEP(EM, BUF)                                                   \
    {                                                                       \
        wb[BUF][lane] = v;                                                  \
        __builtin_amdgcn_wave_barrier();                                    \
        const float4* a4 = reinterpret_cast<const float4*>(wb[BUF]);        \
        float d0 = 0.f, d1 = 0.f, d2 = 0.f, d3 = 0.f;                       \
        float d4 = 0.f, d5 = 0.f, d6 = 0.f, d7 = 0.f;                       \
        _Pragma("unroll")                                                   \
        for (int j4 = 0; j4 < T_ / 8; ++j4) {                               \
            const float4 pa = a4[2 * j4];                                   \
            const float4 pb = a4[2 * j4 + 1];                               \
            d0 = fmaf(pa.x, e[8 * j4 + 0], d0);                             \
            d1 = fmaf(pa.y, e[8 * j4 + 1], d1);                             \
            d2 = fmaf(pa.z, e[8 * j4 + 2], d2);                             \
            d3 = fmaf(pa.w, e[8 * j4 + 3], d3);                             \
            d4 = fmaf(pb.x, e[8 * j4 + 4], d4);                             \
            d5 = fmaf(pb.y, e[8 * j4 + 5], d5);                             \
            d6 = fmaf(pb.z, e[8 * j4 + 6], d6);                             \
            d7 = fmaf(pb.w, e[8 * j4 + 7], d7);                             \
        }                                                                   \
        __builtin_amdgcn_wave_barrier();                                    \
        const float scl = (EM) * invr;      /* both ready a step early */   \
        const float dt  = ((d0 + d4) + (d1 + d5)) + ((d2 + d6) + (d3 + d7));\
        v = dt * scl;                                                       \
        C += lr;                                                            \
        const float r = rfl(v);             /* lag-1: consumed next step */ \
        invr = __builtin_amdgcn_rcpf(r);                                    \
        lr   = __logf(r);                                                   \
    }

    constexpr int PF = 8;
    int s = 1;
    while (s + PF <= len) {
        float emv[PF];
#pragma unroll
        for (int i = 0; i < PF; ++i) emv[i] = em[(s + i) * T_ + col];
#pragma unroll
        for (int i = 0; i < PF; ++i) CRF_STEP(emv[i], ((s + i) & 1));
        s += PF;
    }
    if (s < len) {
        const int rem = len - s;
        float emv[PF];
#pragma unroll
        for (int i = 0; i < PF; ++i)
            if (i < rem) emv[i] = em[(s + i) * T_ + col];
#pragma unroll
        for (int i = 0; i < PF; ++i)
            if (i < rem) CRF_STEP(emv[i], ((s + i) & 1));
    }
#undef CRF_STEP

    // ---- log_Z = C + log(sum_t v_t * exp(end_t)) ----
    float z = (lane < T_) ? v * __expf(end_tr[lane]) : 0.f;
#pragma unroll
    for (int off = 32; off >= 1; off >>= 1)
        z += __shfl_xor(z, off);
    const float logZ = C + __logf(z);

    if (lane == 0) {
        const float num = nsum + start_tr[tg[0]] + end_tr[tg[len - 1]];
        out[b] = num - logZ;
    }
}

// ---------------------------------------------------------------------------
extern "C" void kernel_launch(void* const* d_in, const int* in_sizes, int n_in,
                              void* d_out, int out_size, void* d_ws, size_t ws_size,
                              hipStream_t stream) {
    const float* H        = (const float*)d_in[0];
    const float* W        = (const float*)d_in[1];
    const float* bias     = (const float*)d_in[2];
    const float* start_tr = (const float*)d_in[3];
    const float* end_tr   = (const float*)d_in[4];
    const float* trans    = (const float*)d_in[5];
    const int*   tag      = (const int*)d_in[6];
    const int*   s_len    = (const int*)d_in[7];
    // d_in[8] = w_mask, redundant with s_len

    const size_t NSC = (size_t)B_ * S_ * T_;          // 3,145,728
    float*          scores = (float*)d_ws;
    float*          emit   = scores + NSC;
    unsigned short* Wt     = (unsigned short*)(emit + NSC);  // 96 KB

    hipLaunchKernelGGL(prep_w, dim3(T_), dim3(256), 0, stream, W, Wt);
    hipLaunchKernelGGL(gemm_scores_mfma, dim3((B_ * S_) / 128), dim3(256), 0, stream,
                       H, Wt, bias, s_len, scores, emit);
    hipLaunchKernelGGL(crf_forward, dim3(B_), dim3(64), 0, stream,
                       scores, emit, start_tr, end_tr, trans, tag, s_len,
                       (float*)d_out);
}

// Round 5
// 456.663 us; speedup vs baseline: 2.1254x; 1.0860x over previous
//
#include <hip/hip_runtime.h>
#include <math.h>

#define B_  128
#define S_  512
#define U_  1024
#define T_  48
#define CHK 8       // steps per chunk operator
#define NCH 64      // max chunks per batch = (S-1)/CHK rounded up
#define PLD 72      // P row stride in bf16 elems (144 B, 16B-aligned rows)

typedef short  bf16x8 __attribute__((ext_vector_type(8)));
typedef float  f32x4  __attribute__((ext_vector_type(4)));

__device__ __forceinline__ float rfl(float x) {
    return __int_as_float(__builtin_amdgcn_readfirstlane(__float_as_int(x)));
}
// round-to-nearest fp32 -> bf16 bits, packed pairwise
__device__ __forceinline__ unsigned pack_bf16(float lo, float hi) {
    const unsigned a = __float_as_uint(lo) + 0x8000u;
    const unsigned b = __float_as_uint(hi) + 0x8000u;
    return __builtin_amdgcn_perm(b, a, 0x07060302u);
}

// ===========================================================================
// Kernel 0: Wt[n][k] = bf16(W[k][n])  (one-time transpose for gemm B staging)
// ===========================================================================
__global__ __launch_bounds__(256) void prep_w(
    const float* __restrict__ W, unsigned short* __restrict__ Wt)
{
    const int n = blockIdx.x;                 // 48 blocks
#pragma unroll
    for (int i = 0; i < 4; ++i) {
        const int k = threadIdx.x + 256 * i;
        const unsigned u = __float_as_uint(W[(size_t)k * T_ + n]) + 0x8000u;
        Wt[(size_t)n * U_ + k] = (unsigned short)(u >> 16);
    }
}

// ===========================================================================
// Kernel 1: scores = H @ W + b (fp32). MFMA bf16 16x16x32. (R4-verified,
// emit output removed: exp() now computed where consumed.)
// ===========================================================================
#define KC     64
#define HS_LD  72
#define WS_LD  72

__global__ __launch_bounds__(256) void gemm_scores_mfma(
    const float* __restrict__ H, const unsigned short* __restrict__ Wt,
    const float* __restrict__ bias, const int* __restrict__ s_len,
    float* __restrict__ scores)
{
    __shared__ unsigned short Hs[128 * HS_LD];
    __shared__ unsigned short Ws[T_ * WS_LD];

    const int blk = blockIdx.x;
    const int b   = blk >> 2;
    const int s0  = (blk & 3) * 128;
    if (s0 >= s_len[b]) return;

    const int tid  = threadIdx.x;
    const int wave = tid >> 6;
    const int lane = tid & 63;
    const int m16  = lane & 15;
    const int q    = lane >> 4;
    const int grp  = tid >> 4;
    const int l16  = tid & 15;

    const size_t row0 = (size_t)b * S_ + s0;
    const float* Hg = H + row0 * U_;

    f32x4 acc[2][3];
#pragma unroll
    for (int mt = 0; mt < 2; ++mt)
#pragma unroll
        for (int nt = 0; nt < 3; ++nt) acc[mt][nt] = (f32x4){0.f, 0.f, 0.f, 0.f};

    for (int kc = 0; kc < U_ / KC; ++kc) {
        const int k0 = kc * KC;
#pragma unroll
        for (int p = 0; p < 8; ++p) {
            const int row = p * 16 + grp;
            const float4 h = *reinterpret_cast<const float4*>(
                Hg + (size_t)row * U_ + k0 + l16 * 4);
            const unsigned p01 = pack_bf16(h.x, h.y);
            const unsigned p23 = pack_bf16(h.z, h.w);
            *reinterpret_cast<uint2*>(&Hs[row * HS_LD + l16 * 4]) =
                make_uint2(p01, p23);
        }
#pragma unroll
        for (int i = 0; i < 2; ++i) {
            const int idx = tid + 256 * i;
            if (idx < 384) {
                const int n = idx >> 3, seg = idx & 7;
                const uint4 w = *reinterpret_cast<const uint4*>(
                    Wt + (size_t)n * U_ + k0 + seg * 8);
                *reinterpret_cast<uint4*>(&Ws[n * WS_LD + seg * 8]) = w;
            }
        }
        __syncthreads();

        bf16x8 afr[2][2], bfr[3][2];
#pragma unroll
        for (int mt = 0; mt < 2; ++mt)
#pragma unroll
            for (int ks = 0; ks < 2; ++ks)
                afr[mt][ks] = *reinterpret_cast<const bf16x8*>(
                    &Hs[(wave * 32 + mt * 16 + m16) * HS_LD + ks * 32 + q * 8]);
#pragma unroll
        for (int nt = 0; nt < 3; ++nt)
#pragma unroll
            for (int ks = 0; ks < 2; ++ks)
                bfr[nt][ks] = *reinterpret_cast<const bf16x8*>(
                    &Ws[(nt * 16 + m16) * WS_LD + ks * 32 + q * 8]);
#pragma unroll
        for (int ks = 0; ks < 2; ++ks)
#pragma unroll
            for (int mt = 0; mt < 2; ++mt)
#pragma unroll
                for (int nt = 0; nt < 3; ++nt)
                    acc[mt][nt] = __builtin_amdgcn_mfma_f32_16x16x32_bf16(
                        afr[mt][ks], bfr[nt][ks], acc[mt][nt], 0, 0, 0);
        __syncthreads();
    }

#pragma unroll
    for (int mt = 0; mt < 2; ++mt)
#pragma unroll
        for (int nt = 0; nt < 3; ++nt) {
            const int col = nt * 16 + m16;
            const float bv = bias[col];
#pragma unroll
            for (int i = 0; i < 4; ++i) {
                const size_t r = row0 + wave * 32 + mt * 16 + q * 4 + i;
                scores[r * T_ + col] = acc[mt][nt][i] + bv;
            }
        }
}

// ===========================================================================
// Kernel 2: build chunk operators with MFMA (parallel scan, chunk = 8 steps).
// One wave per (batch, chunk). Maintains P (48x48, row-major bf16 in LDS,
// cols padded to 64 with zeros). Per step computes P_new^T = D_em * E^T * P^T:
//   A = E^T (constant register fragments), B = P^T read as b128 from
//   row-major P, output scaled by em rows and normalized; C-layout writeback
//   lands as ds_write_b64 into row-major P_new. Exports Pt[t][j] = P[j][t]
//   (serial-consumption layout) + accumulated log-scale.
// ===========================================================================
__global__ __launch_bounds__(256) void build_ops(
    const float* __restrict__ scores, const float* __restrict__ trans,
    const int* __restrict__ s_len,
    unsigned short* __restrict__ Ptg, float* __restrict__ logS)
{
    __shared__ float Eld[T_ * T_];                         // exp(trans)[k][m]
    __shared__ __align__(16) unsigned short Pb[4 * 48 * PLD];

    const int tid  = threadIdx.x;
    const int wid  = tid >> 6;
    const int lane = tid & 63;
    const int m16  = lane & 15;
    const int q    = lane >> 4;

    for (int i = tid; i < T_ * T_; i += 256)
        Eld[i] = __expf(trans[i]);
    __syncthreads();                                       // all waves reach

    const int widx = blockIdx.x * 4 + wid;                 // 0..8191
    const int b    = widx >> 6;
    const int c    = widx & (NCH - 1);
    const int len  = s_len[b];
    const int s0   = 1 + c * CHK;
    if (s0 + CHK > len) return;                            // full chunks only

    unsigned short* Ps = &Pb[wid * 48 * PLD];

    // ---- constant A-fragments of E^T: A[m][k] = E[k][m], k>=48 -> 0 ----
    bf16x8 afr[3][2];
#pragma unroll
    for (int mt = 0; mt < 3; ++mt)
#pragma unroll
        for (int kt = 0; kt < 2; ++kt) {
            union { bf16x8 v; unsigned short s[8]; } u;
#pragma unroll
            for (int j = 0; j < 8; ++j) {
                const int k = kt * 32 + q * 8 + j;
                const int m = mt * 16 + m16;
                const float ev = (k < T_) ? Eld[k * T_ + m] : 0.f;
                u.s[j] = (unsigned short)((__float_as_uint(ev) + 0x8000u) >> 16);
            }
            afr[mt][kt] = u.v;
        }

    // ---- init P = Identity (zeros incl. col pad, then diagonal) ----
    {
        uint4* p4 = reinterpret_cast<uint4*>(Ps);
        const uint4 z = make_uint4(0u, 0u, 0u, 0u);
        for (int i = lane; i < 48 * PLD / 8; i += 64) p4[i] = z;
        __builtin_amdgcn_wave_barrier();
        if (lane < T_) Ps[lane * PLD + lane] = 0x3F80;     // bf16(1.0)
        __builtin_amdgcn_wave_barrier();
    }

    const float* sb = scores + ((size_t)b * S_ + s0) * T_;
    float logacc = 0.f;

    // em prefetch: col block mt*16 + q*4 (+i) -> float4 index mt*4+q
    float4 emld[3];
#pragma unroll
    for (int mt = 0; mt < 3; ++mt)
        emld[mt] = reinterpret_cast<const float4*>(sb)[mt * 4 + q];

    for (int i = 0; i < CHK; ++i) {
        float4 em[3];
#pragma unroll
        for (int mt = 0; mt < 3; ++mt) {
            em[mt].x = __expf(emld[mt].x); em[mt].y = __expf(emld[mt].y);
            em[mt].z = __expf(emld[mt].z); em[mt].w = __expf(emld[mt].w);
        }
        if (i + 1 < CHK) {
            const float* sn = sb + (i + 1) * T_;
#pragma unroll
            for (int mt = 0; mt < 3; ++mt)
                emld[mt] = reinterpret_cast<const float4*>(sn)[mt * 4 + q];
        }

        // B-fragments: B[k][n] = P^T[k][n] = P[n][k] -> b128 from row n
        bf16x8 bfr[2][3];
#pragma unroll
        for (int kt = 0; kt < 2; ++kt)
#pragma unroll
            for (int nt = 0; nt < 3; ++nt)
                bfr[kt][nt] = *reinterpret_cast<const bf16x8*>(
                    &Ps[(nt * 16 + m16) * PLD + kt * 32 + q * 8]);

        f32x4 acc[3][3];
#pragma unroll
        for (int mt = 0; mt < 3; ++mt)
#pragma unroll
            for (int nt = 0; nt < 3; ++nt) acc[mt][nt] = (f32x4){0.f,0.f,0.f,0.f};
#pragma unroll
        for (int kt = 0; kt < 2; ++kt)
#pragma unroll
            for (int mt = 0; mt < 3; ++mt)
#pragma unroll
                for (int nt = 0; nt < 3; ++nt)
                    acc[mt][nt] = __builtin_amdgcn_mfma_f32_16x16x32_bf16(
                        afr[mt][kt], bfr[kt][nt], acc[mt][nt], 0, 0, 0);

        // normalize by D[0][0]*em[0] (lane 0 holds it), scale rows by em
        const float r    = rfl(acc[0][0][0] * em[0].x);
        const float rinv = __builtin_amdgcn_rcpf(r);
        logacc += __logf(r);
        __builtin_amdgcn_wave_barrier();
#pragma unroll
        for (int mt = 0; mt < 3; ++mt) {
            const float sx = em[mt].x * rinv, sy = em[mt].y * rinv;
            const float sz = em[mt].z * rinv, sw = em[mt].w * rinv;
#pragma unroll
            for (int nt = 0; nt < 3; ++nt) {
                const unsigned lo = pack_bf16(acc[mt][nt][0] * sx,
                                              acc[mt][nt][1] * sy);
                const unsigned hi = pack_bf16(acc[mt][nt][2] * sz,
                                              acc[mt][nt][3] * sw);
                // D[m][n] = P_new[n][m]: row n = nt*16+m16, cols mt*16+q*4..+3
                *reinterpret_cast<uint2*>(
                    &Ps[(nt * 16 + m16) * PLD + mt * 16 + q * 4]) =
                    make_uint2(lo, hi);
            }
        }
        __builtin_amdgcn_wave_barrier();
    }

    // ---- export transposed operator: Pt[t][j] = P[j][t]  (48x48 bf16) ----
    if (lane < T_) {
        unsigned outp[24];
#pragma unroll
        for (int j2 = 0; j2 < 24; ++j2) {
            const unsigned a  = Ps[(2 * j2)     * PLD + lane];
            const unsigned b2 = Ps[(2 * j2 + 1) * PLD + lane];
            outp[j2] = a | (b2 << 16);
        }
        unsigned short* dst =
            Ptg + (((size_t)b * NCH + c) * 48 + lane) * 48;
        uint4* d4 = reinterpret_cast<uint4*>(dst);
#pragma unroll
        for (int t4 = 0; t4 < 6; ++t4)
            d4[t4] = make_uint4(outp[4*t4], outp[4*t4+1],
                                outp[4*t4+2], outp[4*t4+3]);
    }
    if (lane == 0) logS[(size_t)b * NCH + c] = logacc;
}

// ===========================================================================
// Kernel 3: CRF forward + numerator. One wave per batch.
// Serial iterations: 63 chunk-steps (v' = v * Pt_chunk, operator prefetched
// double-buffered from global) + <=7 tail steps + numerator. Lag-1
// normalization identical to R4 (verified absmax 0).
// ===========================================================================
__global__ __launch_bounds__(64) void crf_forward(
    const float* __restrict__ scores, const unsigned short* __restrict__ Ptg,
    const float* __restrict__ logS,
    const float* __restrict__ start_tr, const float* __restrict__ end_tr,
    const float* __restrict__ trans, const int* __restrict__ tag,
    const int* __restrict__ s_len, float* __restrict__ out)
{
    __shared__ float E[T_ * T_];
    __shared__ float Tr[T_ * T_];
    __shared__ __align__(16) float wb[2][64];

    const int b    = blockIdx.x;
    const int lane = threadIdx.x;

    for (int i = lane; i < T_ * T_; i += 64) {
        const float t = trans[i];
        Tr[i] = t;
        E[i]  = __expf(t);
    }
    __syncthreads();

    const int len = s_len[b];                       // [1, S]
    const float* sc = scores + (size_t)b * S_ * T_;
    const int*   tg = tag + (size_t)b * S_;

    // ---- numerator ----
    float nsum = 0.f;
    for (int s = lane; s < len; s += 64) {
        const int t = tg[s];
        nsum += sc[s * T_ + t];
        if (s >= 1) nsum += Tr[tg[s - 1] * T_ + t];
    }
#pragma unroll
    for (int off = 32; off >= 1; off >>= 1)
        nsum += __shfl_xor(nsum, off);

    const int col = (lane < T_) ? lane : 0;

    // ---- init from step 0 ----
    const float lp0 = (lane < T_) ? (start_tr[lane] + sc[lane]) : -1e30f;
    const float m0  = rfl(lp0);
    float v = __expf(lp0 - m0);
    float C = m0;
    float invr = 1.0f, lr = 0.0f;
    int par = 0;

    // ---- chunk phase ----
    const int F = (len - 1) / CHK;
    const unsigned short* Pb_ = Ptg + (size_t)b * NCH * 48 * 48;
    const float* Lb = logS + (size_t)b * NCH;

    uint4 cur[6], nxt[6];
    float ls_cur = 0.f, ls_nxt = 0.f;
    if (F > 0) {
        const uint4* p = reinterpret_cast<const uint4*>(Pb_ + (size_t)col * 48);
#pragma unroll
        for (int i = 0; i < 6; ++i) cur[i] = p[i];
        ls_cur = Lb[0];
    }
    for (int cc = 0; cc < F; ++cc) {
        if (cc + 1 < F) {
            const uint4* p = reinterpret_cast<const uint4*>(
                Pb_ + (size_t)(cc + 1) * 2304 + (size_t)col * 48);
#pragma unroll
            for (int i = 0; i < 6; ++i) nxt[i] = p[i];
            ls_nxt = Lb[cc + 1];
        }
        // unpack this lane's operator row (bf16 -> fp32)
        float pr[48];
#pragma unroll
        for (int i = 0; i < 6; ++i) {
            const uint4 u = cur[i];
            pr[8*i+0] = __uint_as_float(u.x << 16);
            pr[8*i+1] = __uint_as_float(u.x & 0xFFFF0000u);
            pr[8*i+2] = __uint_as_float(u.y << 16);
            pr[8*i+3] = __uint_as_float(u.y & 0xFFFF0000u);
            pr[8*i+4] = __uint_as_float(u.z << 16);
            pr[8*i+5] = __uint_as_float(u.z & 0xFFFF0000u);
            pr[8*i+6] = __uint_as_float(u.w << 16);
            pr[8*i+7] = __uint_as_float(u.w & 0xFFFF0000u);
        }
        // broadcast v, dot with pr
        wb[par & 1][lane] = v;
        __builtin_amdgcn_wave_barrier();
        const float4* a4 = reinterpret_cast<const float4*>(wb[par & 1]);
        float d0=0.f,d1=0.f,d2=0.f,d3=0.f,d4=0.f,d5=0.f,d6=0.f,d7=0.f;
#pragma unroll
        for (int j4 = 0; j4 < 6; ++j4) {
            const float4 pa = a4[2 * j4];
            const float4 pb = a4[2 * j4 + 1];
            d0 = fmaf(pa.x, pr[8*j4+0], d0);
            d1 = fmaf(pa.y, pr[8*j4+1], d1);
            d2 = fmaf(pa.z, pr[8*j4+2], d2);
            d3 = fmaf(pa.w, pr[8*j4+3], d3);
            d4 = fmaf(pb.x, pr[8*j4+4], d4);
            d5 = fmaf(pb.y, pr[8*j4+5], d5);
            d6 = fmaf(pb.z, pr[8*j4+6], d6);
            d7 = fmaf(pb.w, pr[8*j4+7], d7);
        }
        __builtin_amdgcn_wave_barrier();
        const float dt = ((d0 + d4) + (d1 + d5)) + ((d2 + d6) + (d3 + d7));
        v = dt * invr;
        C += lr + ls_cur;
        const float r = rfl(v);
        invr = __builtin_amdgcn_rcpf(r);
        lr   = __logf(r);
        par ^= 1;
#pragma unroll
        for (int i = 0; i < 6; ++i) cur[i] = nxt[i];
        ls_cur = ls_nxt;
    }

    // ---- tail steps (<= CHK-1), per-step recursion with E column ----
    float e[T_];
#pragma unroll
    for (int j = 0; j < T_; ++j) e[j] = E[j * T_ + col];

#define CRF_STEP(EM, BUF)                                                   \
    {                                                                       \
        wb[BUF][lane] = v;                                                  \
        __builtin_amdgcn_wave_barrier();                                    \
        const float4* a4t = reinterpret_cast<const float4*>(wb[BUF]);       \
        float t0=0.f,t1=0.f,t2=0.f,t3=0.f,t4=0.f,t5=0.f,t6=0.f,t7=0.f;      \
        _Pragma("unroll")                                                   \
        for (int j4 = 0; j4 < 6; ++j4) {                                    \
            const float4 pa = a4t[2 * j4];                                  \
            const float4 pb = a4t[2 * j4 + 1];                              \
            t0 = fmaf(pa.x, e[8*j4+0], t0);                                 \
            t1 = fmaf(pa.y, e[8*j4+1], t1);                                 \
            t2 = fmaf(pa.z, e[8*j4+2], t2);                                 \
            t3 = fmaf(pa.w, e[8*j4+3], t3);                                 \
            t4 = fmaf(pb.x, e[8*j4+4], t4);                                 \
            t5 = fmaf(pb.y, e[8*j4+5], t5);                                 \
            t6 = fmaf(pb.z, e[8*j4+6], t6);                                 \
            t7 = fmaf(pb.w, e[8*j4+7], t7);                                 \
        }                                                                   \
        __builtin_amdgcn_wave_barrier();                                    \
        const float scl = (EM) * invr;                                      \
        const float dtt = ((t0 + t4) + (t1 + t5)) + ((t2 + t6) + (t3 + t7));\
        v = dtt * scl;                                                      \
        C += lr;                                                            \
        const float r2 = rfl(v);                                            \
        invr = __builtin_amdgcn_rcpf(r2);                                   \
        lr   = __logf(r2);                                                  \
    }

    const int st = 1 + F * CHK;
    if (st < len) {
        const int rem = len - st;                   // 1..7
        float emv[CHK - 1];
#pragma unroll
        for (int i = 0; i < CHK - 1; ++i)
            if (i < rem) emv[i] = __expf(sc[(st + i) * T_ + col]);
#pragma unroll
        for (int i = 0; i < CHK - 1; ++i)
            if (i < rem) { CRF_STEP(emv[i], (par & 1)); par ^= 1; }
    }
#undef CRF_STEP

    // ---- log_Z = C + log(sum_t v_t * exp(end_t)) ----
    float z = (lane < T_) ? v * __expf(end_tr[lane]) : 0.f;
#pragma unroll
    for (int off = 32; off >= 1; off >>= 1)
        z += __shfl_xor(z, off);
    const float logZ = C + __logf(z);

    if (lane == 0) {
        const float num = nsum + start_tr[tg[0]] + end_tr[tg[len - 1]];
        out[b] = num - logZ;
    }
}

// ---------------------------------------------------------------------------
extern "C" void kernel_launch(void* const* d_in, const int* in_sizes, int n_in,
                              void* d_out, int out_size, void* d_ws, size_t ws_size,
                              hipStream_t stream) {
    const float* H        = (const float*)d_in[0];
    const float* W        = (const float*)d_in[1];
    const float* bias     = (const float*)d_in[2];
    const float* start_tr = (const float*)d_in[3];
    const float* end_tr   = (const float*)d_in[4];
    const float* trans    = (const float*)d_in[5];
    const int*   tag      = (const int*)d_in[6];
    const int*   s_len    = (const int*)d_in[7];
    // d_in[8] = w_mask, redundant with s_len

    const size_t NSC = (size_t)B_ * S_ * T_;                 // 3,145,728
    float*          scores = (float*)d_ws;                   // 12.6 MB
    float*          logS   = scores + NSC;                   // 32 KB
    unsigned short* Wt     = (unsigned short*)(logS + B_ * NCH);  // 96 KB
    unsigned short* Ptg    = Wt + (size_t)T_ * U_;           // 37.7 MB

    hipLaunchKernelGGL(prep_w, dim3(T_), dim3(256), 0, stream, W, Wt);
    hipLaunchKernelGGL(gemm_scores_mfma, dim3((B_ * S_) / 128), dim3(256), 0,
                       stream, H, Wt, bias, s_len, scores);
    hipLaunchKernelGGL(build_ops, dim3(B_ * NCH / 4), dim3(256), 0, stream,
                       scores, trans, s_len, Ptg, logS);
    hipLaunchKernelGGL(crf_forward, dim3(B_), dim3(64), 0, stream,
                       scores, Ptg, logS, start_tr, end_tr, trans, tag, s_len,
                       (float*)d_out);
}